// Round 18
// baseline (162.537 us; speedup 1.0000x reference)
//
#include <hip/hip_runtime.h>
#include <hip/hip_bf16.h>
#include <math.h>

// Problem constants (fixed shapes from setup_inputs)
#define S_LEN 2048
#define NH 16
#define HD 64
#define DM 1024
#define NTOK 4096   // B*S
#define NBH 32      // B*NH

typedef __attribute__((ext_vector_type(8))) __bf16 bf16x8;
typedef __attribute__((ext_vector_type(8))) ushort ushort8;
typedef __attribute__((ext_vector_type(4))) ushort ushort4v;
typedef __attribute__((ext_vector_type(4))) float f32x4;
typedef __attribute__((ext_vector_type(16))) float f32x16;
typedef __attribute__((ext_vector_type(4))) uint u32x4;

__device__ __forceinline__ ushort f2b(float x) {
  __hip_bfloat16 h = __float2bfloat16(x);
  return *reinterpret_cast<ushort*>(&h);
}

__device__ __forceinline__ uint pk2(float lo, float hi) {
  return (uint)f2b(lo) | ((uint)f2b(hi) << 16);
}

// raw v_exp_f32 (exp2) — libm exp2f goes through __ocml with special-case handling
#define EXP2(x) __builtin_amdgcn_exp2f(x)

__device__ __forceinline__ void gload16b(const void* g, void* l) {
  __builtin_amdgcn_global_load_lds((const __attribute__((address_space(1))) void*)g,
                                   (__attribute__((address_space(3))) void*)l, 16, 0, 0);
}

#define MFMA16(a, b, c) __builtin_amdgcn_mfma_f32_16x16x32_bf16((a), (b), (c), 0, 0, 0)
#define MFMA32(a, b, c) __builtin_amdgcn_mfma_f32_32x32x16_bf16((a), (b), (c), 0, 0, 0)

// ---------------------------------------------------------------- convert fp32 -> bf16
struct CvtArgs {
  const float* src[7];
  ushort* dst[7];
  int n[7];
};

__global__ void cvt_kernel(CvtArgs a) {
  int arr = blockIdx.y;
  const float* s = a.src[arr];
  ushort* d = a.dst[arr];
  long n = a.n[arr];
  for (long i = ((long)blockIdx.x * 256 + threadIdx.x) * 8; i < n; i += 512L * 256 * 8) {
    float4 v0 = *reinterpret_cast<const float4*>(s + i);
    float4 v1 = *reinterpret_cast<const float4*>(s + i + 4);
    ushort8 r;
    r[0] = f2b(v0.x); r[1] = f2b(v0.y); r[2] = f2b(v0.z); r[3] = f2b(v0.w);
    r[4] = f2b(v1.x); r[5] = f2b(v1.y); r[6] = f2b(v1.z); r[7] = f2b(v1.w);
    *reinterpret_cast<ushort8*>(d + i) = r;
  }
}

// ---------------------------------------------------------------- fused QK/V projection
// 128x128xBK32, 256 threads. B1 (phi weights) now loaded to REGISTERS from L2
// (bp[4], addresses static, weight is L2-resident) -> LDS drops 72KB -> 32KB
// (A+B0 double-buffer) -> 3 blocks/CU at VGPR ~130, NO spill (R16 lesson: never
// cap VGPR; R17 analysis: the occupancy limit was LDS, so shrink LDS instead).
// vmcnt ledger (order at body end: barrier2 -> ldbp(kt+1) -> stage(kt+2)):
//   top wait: newer-than-stage(kt) = bp(kt)[4] + stage(kt+1)[4] = 8 -> vmcnt(8)
//   (tail kt==nk-1: only bp(kt) newer -> vmcnt(4)); compiler's auto-wait before
//   the accP MFMAs counts the 4 stage loads issued after bp -> vmcnt(4), leaving
//   the stage prefetch in flight. q-scale folds log2(e) -> exp2-domain softmax.
__global__ __launch_bounds__(256, 2) void qkproj_kernel(
    const ushort* __restrict__ A,
    const ushort* __restrict__ Wqa, const ushort* __restrict__ Wqp,
    const ushort* __restrict__ Wka, const ushort* __restrict__ Wkp,
    const ushort* __restrict__ Wv, const float* __restrict__ sls,
    ushort* __restrict__ qext, ushort* __restrict__ kext, ushort* __restrict__ vT) {
  __shared__ __align__(16) ushort Alds[2][4096];
  __shared__ __align__(16) ushort B0lds[2][4096];
  const int d = blockIdx.x;
  const int xc = d & 7, c = d >> 3;  // c in 0..95
  const int u = (c < 64) ? (xc * 64 + c) : (512 + xc * 32 + (c - 64));
  int z, bx, by;
  if (u < 512) { z = u >> 8; int v = u & 255; bx = v & 7; by = v >> 3; }
  else         { z = 2;      int v = u - 512; bx = v & 7; by = v >> 3; }
  const int t = threadIdx.x;
  const int lane = t & 63;
  const int wave = t >> 6;
  const int wm = wave >> 1, wn = wave & 1;
  const int l15 = lane & 15, g = lane >> 4;
  const int mbase = by * 128, nbase = bx * 128;
  const int K = DM;
  const int srow = t >> 2;
  const int sx = (srow >> 1) & 3;            // inverse source swizzle
  const int scol = (((t & 3) ^ sx)) * 8;
  const int xr = (l15 >> 1) & 3;             // read-side swizzle
  const ushort* Ag = A + (size_t)(mbase + srow) * K + scol;
  const ushort* Wa = (z == 0) ? Wqa : (z == 1) ? Wka : Wv;
  const ushort* Wp = (z == 0) ? Wqp : Wkp;
  const ushort* Wag = Wa + (size_t)(nbase + srow) * K + scol;

  const int nk = K / 32;
  f32x4 accA[4][4] = {};

  // A + B0 staging (4 loads), double-buffered, staged at body END (after barrier2)
  auto stage = [&](int buf, int kt) {
    gload16b(Ag + kt, &Alds[buf][t * 8]);
    gload16b(Ag + kt + (size_t)64 * K, &Alds[buf][t * 8 + 64 * 32]);
    gload16b(Wag + kt, &B0lds[buf][t * 8]);
    gload16b(Wag + kt + (size_t)64 * K, &B0lds[buf][t * 8 + 64 * 32]);
  };

  if (z < 2) {
    f32x4 accP[4][4] = {};
    // per-wave phi-weight fragment base: row (nbase + wn*64 + j*16 + l15), col g*8
    const ushort* Wpr = Wp + (size_t)(nbase + wn * 64 + l15) * K + g * 8;
    bf16x8 bp[4];
    auto ldbp = [&](int kt) {
#pragma unroll
      for (int j = 0; j < 4; j++)
        bp[j] = *reinterpret_cast<const bf16x8*>(Wpr + (size_t)(j * 16) * K + kt);
    };
    stage(0, 0);
    ldbp(0);
    stage(1, 32);
    for (int kt = 0; kt < nk; ++kt) {
      const int cur = kt & 1;
      if (kt + 1 < nk) asm volatile("s_waitcnt vmcnt(8)" ::: "memory");
      else             asm volatile("s_waitcnt vmcnt(4)" ::: "memory");
      __builtin_amdgcn_s_barrier();   // buf[cur] staged by all waves
      bf16x8 af[4], ba[4];
#pragma unroll
      for (int i = 0; i < 4; i++)
        af[i] = *reinterpret_cast<const bf16x8*>(
            &Alds[cur][(wm * 64 + i * 16 + l15) * 32 + (g ^ xr) * 8]);
#pragma unroll
      for (int j = 0; j < 4; j++)
        ba[j] = *reinterpret_cast<const bf16x8*>(
            &B0lds[cur][(wn * 64 + j * 16 + l15) * 32 + (g ^ xr) * 8]);
      __builtin_amdgcn_s_setprio(1);
#pragma unroll
      for (int i = 0; i < 4; i++)
#pragma unroll
        for (int j = 0; j < 4; j++)
          accA[i][j] = MFMA16(af[i], ba[j], accA[i][j]);
      // accP uses bp (register operand); compiler inserts the vmcnt for bp here
#pragma unroll
      for (int i = 0; i < 4; i++)
#pragma unroll
        for (int j = 0; j < 4; j++)
          accP[i][j] = MFMA16(af[i], bp[j], accP[i][j]);
      __builtin_amdgcn_s_setprio(0);
      __builtin_amdgcn_s_barrier();   // all waves done reading buf[cur]
      if (kt + 1 < nk) ldbp((kt + 1) * 32);   // bp for next iter (before stage!)
      if (kt + 2 < nk) stage(cur, (kt + 2) * 32);
    }
    const int row0 = mbase + wm * 64;
    const int h = (nbase >> 6) + wn;
    // q-scale folds exp(sls)/8 AND log2(e) -> attention exp becomes exp2
    const float scale = (z == 0) ? __expf(sls[h]) * 0.125f * 1.44269504f : 1.0f;
    ushort* ext = (z == 0) ? qext : kext;
#pragma unroll
    for (int i = 0; i < 4; i++) {
#pragma unroll
      for (int r = 0; r < 4; r++) {
        float sp[4];
        float ss = 0.0f;
#pragma unroll
        for (int j = 0; j < 4; j++) {
          float v = accA[i][j][r];
          sp[j] = fmaxf(v, 0.0f) + __logf(1.0f + __expf(-fabsf(v)));
          ss += sp[j] * sp[j];
        }
        ss += __shfl_xor(ss, 1);
        ss += __shfl_xor(ss, 2);
        ss += __shfl_xor(ss, 4);
        ss += __shfl_xor(ss, 8);
        float rn = rsqrtf(ss * (1.0f / 64.0f) + 1e-6f) * scale;
        const int token = row0 + i * 16 + g * 4 + r;
        const int bb = token >> 11, sidx = token & 2047;
        ushort* base = ext + (((size_t)(bb * NH + h) * S_LEN + sidx) << 7);
#pragma unroll
        for (int j = 0; j < 4; j++) {
          float e = __expf(2.0f * accP[i][j][r]);
          float th = 1.0f - 2.0f * __builtin_amdgcn_rcpf(e + 1.0f);
          float phi = 3.14159265358979f * th;
          float sn = __sinf(phi), cs = __cosf(phi);
          float a = sp[j] * rn;
          int dd = j * 16 + l15;
          base[dd] = f2b(a * cs);
          base[64 + dd] = f2b(a * sn);
        }
      }
    }
  } else {
    // ---------------- V GEMM -> vT directly; dbuf, stage at body end ----------------
    stage(0, 0);
    stage(1, 32);
    for (int kt = 0; kt < nk; ++kt) {
      const int cur = kt & 1;
      if (kt + 1 < nk) asm volatile("s_waitcnt vmcnt(4)" ::: "memory");
      else             asm volatile("s_waitcnt vmcnt(0)" ::: "memory");
      __builtin_amdgcn_s_barrier();
      bf16x8 af[4], ba[4];
#pragma unroll
      for (int i = 0; i < 4; i++)
        af[i] = *reinterpret_cast<const bf16x8*>(
            &Alds[cur][(wm * 64 + i * 16 + l15) * 32 + (g ^ xr) * 8]);
#pragma unroll
      for (int j = 0; j < 4; j++)
        ba[j] = *reinterpret_cast<const bf16x8*>(
            &B0lds[cur][(wn * 64 + j * 16 + l15) * 32 + (g ^ xr) * 8]);
      __builtin_amdgcn_s_setprio(1);
#pragma unroll
      for (int i = 0; i < 4; i++)
#pragma unroll
        for (int j = 0; j < 4; j++)
          accA[i][j] = MFMA16(af[i], ba[j], accA[i][j]);
      __builtin_amdgcn_s_setprio(0);
      __builtin_amdgcn_s_barrier();
      if (kt + 2 < nk) stage(cur, (kt + 2) * 32);
    }
    const int row0 = mbase + wm * 64, col0 = nbase + wn * 64;
#pragma unroll
    for (int i = 0; i < 4; i++)
#pragma unroll
      for (int j = 0; j < 4; j++) {
        int col = col0 + j * 16 + l15;
        int h = col >> 6, hd = col & 63;
        int t0 = row0 + i * 16 + g * 4;
        int bb = t0 >> 11, s0 = t0 & 2047;
        ushort4v w;
#pragma unroll
        for (int r = 0; r < 4; r++) w[r] = f2b(accA[i][j][r]);
        *reinterpret_cast<ushort4v*>(
            &vT[(((size_t)(bb * NH + h) * HD + hd) << 11) + s0]) = w;
      }
  }
}

// ---------------------------------------------------------------- GEMM (Wo projection)
__global__ __launch_bounds__(256) void gemm_bt(const ushort* __restrict__ A,
                                               const ushort* __restrict__ W,
                                               float* __restrict__ Cout,
                                               int M, int N, int K) {
  __shared__ __align__(16) ushort Alds[4][4096];
  __shared__ __align__(16) ushort Blds[4][4096];
  const int d = blockIdx.x;
  const int u = (d & 7) * 32 + (d >> 3);
  const int bx = u & 7, by = u >> 3;
  const int t = threadIdx.x;
  const int lane = t & 63;
  const int wave = t >> 6;
  const int wm = wave >> 1, wn = wave & 1;
  const int l15 = lane & 15, g = lane >> 4;
  const int mbase = by * 128, nbase = bx * 128;
  const int srow = t >> 2;
  const int sx = (srow >> 1) & 3;
  const int scol = (((t & 3) ^ sx)) * 8;
  const int xr = (l15 >> 1) & 3;
  const ushort* Ag = A + (size_t)(mbase + srow) * K + scol;
  const ushort* Wg = W + (size_t)(nbase + srow) * K + scol;
  auto stage = [&](int buf, int kt) {
    gload16b(Ag + kt, &Alds[buf][t * 8]);
    gload16b(Ag + kt + (size_t)64 * K, &Alds[buf][t * 8 + 64 * 32]);
    gload16b(Wg + kt, &Blds[buf][t * 8]);
    gload16b(Wg + kt + (size_t)64 * K, &Blds[buf][t * 8 + 64 * 32]);
  };
  const int nk = K / 32;
  stage(0, 0);
  stage(1, 32);
  stage(2, 64);
  f32x4 acc[4][4] = {};
  for (int kt = 0; kt < nk; ++kt) {
    const int cur = kt & 3;
    if (kt + 3 < nk) {
      stage((cur + 3) & 3, (kt + 3) * 32);
      asm volatile("s_waitcnt vmcnt(12)" ::: "memory");
    } else if (kt + 2 < nk) {
      asm volatile("s_waitcnt vmcnt(8)" ::: "memory");
    } else if (kt + 1 < nk) {
      asm volatile("s_waitcnt vmcnt(4)" ::: "memory");
    } else {
      asm volatile("s_waitcnt vmcnt(0)" ::: "memory");
    }
    __builtin_amdgcn_s_barrier();
    bf16x8 af[4], bfr[4];
#pragma unroll
    for (int i = 0; i < 4; i++)
      af[i] = *reinterpret_cast<const bf16x8*>(
          &Alds[cur][(wm * 64 + i * 16 + l15) * 32 + (g ^ xr) * 8]);
#pragma unroll
    for (int j = 0; j < 4; j++)
      bfr[j] = *reinterpret_cast<const bf16x8*>(
          &Blds[cur][(wn * 64 + j * 16 + l15) * 32 + (g ^ xr) * 8]);
    __builtin_amdgcn_s_setprio(1);
#pragma unroll
    for (int i = 0; i < 4; i++)
#pragma unroll
      for (int j = 0; j < 4; j++)
        acc[i][j] = MFMA16(af[i], bfr[j], acc[i][j]);
    __builtin_amdgcn_s_setprio(0);
    __builtin_amdgcn_s_barrier();
  }
  const int row0 = mbase + wm * 64, col0 = nbase + wn * 64;
#pragma unroll
  for (int i = 0; i < 4; i++)
#pragma unroll
    for (int j = 0; j < 4; j++)
#pragma unroll
      for (int r = 0; r < 4; r++) {
        int row = row0 + i * 16 + g * 4 + r;
        int col = col0 + j * 16 + l15;
        Cout[(size_t)row * N + col] = acc[i][j][r];
      }
}

// ---------------------------------------------------------------- causal flash attention
// Softmax in exp2 domain via raw v_exp_f32 (log2(e) folded into q-scale).
// Defer-max threshold 11.5416 (= 8*log2e, P bound e^8 unchanged).
__device__ __forceinline__ void stage_kv(const char* Kp, const char* Vp, int kb,
                                         char* buf, int wave, int lane) {
#pragma unroll
  for (int c = 0; c < 4; c++) {
    int i = wave * 4 + c;
    int kvl = i * 4 + (lane >> 4);
    int slot = (lane & 15) ^ (kvl & 7);
    gload16b(Kp + (size_t)(kb + kvl) * 256 + slot * 16, buf + i * 1024);
  }
#pragma unroll
  for (int c = 0; c < 2; c++) {
    int i = wave * 2 + c;
    int hd = i * 8 + (lane >> 3);
    int slot = (lane & 7) ^ (hd & 7);
    gload16b(Vp + (size_t)hd * (S_LEN * 2) + (size_t)kb * 2 + slot * 16,
             buf + 16384 + i * 1024);
  }
}

__global__ __launch_bounds__(256, 3) void attn_kernel(const ushort* __restrict__ qext,
                                                      const ushort* __restrict__ kext,
                                                      const ushort* __restrict__ vT,
                                                      ushort* __restrict__ attnout,
                                                      float* __restrict__ part) {
  __shared__ __align__(16) char lds[2][24576];
  const int d = blockIdx.x;
  const int xcd = d & 7, c = d >> 3;          // c in 0..95
  const int bh = xcd * 4 + (c & 3);           // 4 heads per XCD
  const int w = c >> 2;                       // 0..23
  int qt, t0, t1, half;
  bool split;
  if (w < 8) { qt = w; t0 = 0; t1 = 2 * qt + 1; split = false; half = 0; }
  else {
    int ww = w - 8;
    qt = 8 + (ww >> 1); half = ww & 1; split = true;
    if (half == 0) { t0 = 0; t1 = qt; } else { t0 = qt + 1; t1 = 2 * qt + 1; }
  }
  const int b = bh >> 4, h = bh & 15;
  const int wave = threadIdx.x >> 6, lane = threadIdx.x & 63;
  const int l31 = lane & 31, hi = lane >> 5;
  const int qb = qt * 128;
  const int qw = qb + wave * 32;
  const int qa = qw + l31;
  const char* Kp = (const char*)(kext + (size_t)bh * S_LEN * 128);
  const char* Vp = (const char*)(vT + (size_t)bh * HD * S_LEN);
  const ushort* Qp = qext + (size_t)bh * S_LEN * 128;
  const int ksw = l31 & 7;

  stage_kv(Kp, Vp, t0 << 6, lds[0], wave, lane);
  bf16x8 qf[8];
#pragma unroll
  for (int s = 0; s < 8; s++)
    qf[s] = *reinterpret_cast<const bf16x8*>(&Qp[(size_t)qa * 128 + s * 16 + hi * 8]);

  f32x16 o0 = {}, o1 = {};
  float m = -1e30f, ls = 0.0f;

  for (int t = t0; t <= t1; ++t) {
    const int cur = (t - t0) & 1;
    const int kb = t << 6;
    if (t < t1) {
      stage_kv(Kp, Vp, (t + 1) << 6, lds[cur ^ 1], wave, lane);
      asm volatile("s_waitcnt vmcnt(6)" ::: "memory");
    } else {
      asm volatile("s_waitcnt vmcnt(0)" ::: "memory");
    }
    __builtin_amdgcn_s_barrier();

    const char* Kb = lds[cur];
    const char* Vb = lds[cur] + 16384;

    f32x16 st0 = {}, st1 = {};
    __builtin_amdgcn_s_setprio(1);
#pragma unroll
    for (int s = 0; s < 8; s++) {
      int sl = ((s * 2 + hi) ^ ksw) << 4;
      bf16x8 k0 = *(const bf16x8*)(Kb + l31 * 256 + sl);
      bf16x8 k1 = *(const bf16x8*)(Kb + (32 + l31) * 256 + sl);
      st0 = MFMA32(k0, qf[s], st0);
      st1 = MFMA32(k1, qf[s], st1);
    }
    __builtin_amdgcn_s_setprio(0);

    if (kb + 64 > qw) {
#pragma unroll
      for (int r = 0; r < 16; r++) {
        int kv = kb + (r & 3) + 8 * (r >> 2) + 4 * hi;
        if (kv > qa) st0[r] = -1e30f;
        if (kv + 32 > qa) st1[r] = -1e30f;
      }
    }
    float pm = -1e30f;
#pragma unroll
    for (int r = 0; r < 16; r++) pm = fmaxf(pm, fmaxf(st0[r], st1[r]));
    pm = fmaxf(pm, __shfl_xor(pm, 32));
    if (!__all(pm <= m + 11.5416f)) {   // 8 * log2(e): bound e^8, exp2 domain
      float mn = fmaxf(m, pm);
      float corr = EXP2(m - mn);
      m = mn;
      ls *= corr;
#pragma unroll
      for (int r = 0; r < 16; r++) { o0[r] *= corr; o1[r] *= corr; }
    }
    float ssum = 0.0f;
#pragma unroll
    for (int r = 0; r < 16; r++) {
      st0[r] = EXP2(st0[r] - m);
      st1[r] = EXP2(st1[r] - m);
      ssum += st0[r] + st1[r];
    }
    ssum += __shfl_xor(ssum, 32);
    ls += ssum;

    u32x4 pb[4];
#pragma unroll
    for (int hf = 0; hf < 2; hf++) {
      const f32x16& st = hf ? st1 : st0;
      uint cA0 = pk2(st[0], st[1]),  cA1 = pk2(st[2], st[3]);
      uint cB0 = pk2(st[4], st[5]),  cB1 = pk2(st[6], st[7]);
      uint cC0 = pk2(st[8], st[9]),  cC1 = pk2(st[10], st[11]);
      uint cD0 = pk2(st[12], st[13]), cD1 = pk2(st[14], st[15]);
      uint xA0 = __shfl_xor(cA0, 32), xA1 = __shfl_xor(cA1, 32);
      uint xB0 = __shfl_xor(cB0, 32), xB1 = __shfl_xor(cB1, 32);
      uint xC0 = __shfl_xor(cC0, 32), xC1 = __shfl_xor(cC1, 32);
      uint xD0 = __shfl_xor(cD0, 32), xD1 = __shfl_xor(cD1, 32);
      u32x4 lo, hi4;
      lo[0] = cA0; lo[1] = cA1; lo[2] = xA0; lo[3] = xA1;
      hi4[0] = xB0; hi4[1] = xB1; hi4[2] = cB0; hi4[3] = cB1;
      pb[hf * 2] = hi ? hi4 : lo;
      u32x4 lo2, hi2;
      lo2[0] = cC0; lo2[1] = cC1; lo2[2] = xC0; lo2[3] = xC1;
      hi2[0] = xD0; hi2[1] = xD1; hi2[2] = cD0; hi2[3] = cD1;
      pb[hf * 2 + 1] = hi ? hi2 : lo2;
    }
    __builtin_amdgcn_s_setprio(1);
#pragma unroll
    for (int ks = 0; ks < 4; ks++) {
      int sl = ((ks * 2 + hi) ^ ksw) << 4;
      bf16x8 v0 = *(const bf16x8*)(Vb + l31 * 128 + sl);
      bf16x8 v1 = *(const bf16x8*)(Vb + (32 + l31) * 128 + sl);
      bf16x8 pbb = *reinterpret_cast<const bf16x8*>(&pb[ks]);
      o0 = MFMA32(v0, pbb, o0);
      o1 = MFMA32(v1, pbb, o1);
    }
    __builtin_amdgcn_s_setprio(0);
    __builtin_amdgcn_s_barrier();
  }

  if (!split) {
    float inv = 1.0f / ls;
    ushort* Op = attnout + ((size_t)b * S_LEN + qa) * DM + h * HD;
#pragma unroll
    for (int g4 = 0; g4 < 4; g4++) {
      ushort4v w0, w1;
#pragma unroll
      for (int jj = 0; jj < 4; jj++) {
        w0[jj] = f2b(o0[4 * g4 + jj] * inv);
        w1[jj] = f2b(o1[4 * g4 + jj] * inv);
      }
      *reinterpret_cast<ushort4v*>(Op + 8 * g4 + 4 * hi) = w0;
      *reinterpret_cast<ushort4v*>(Op + 32 + 8 * g4 + 4 * hi) = w1;
    }
  } else {
    float* P = part + ((size_t)(half * 256 + bh * 8 + (qt - 8)) * 128
                       + (wave * 32 + l31)) * 72;
#pragma unroll
    for (int g4 = 0; g4 < 4; g4++) {
      float4 a0 = make_float4(o0[4 * g4], o0[4 * g4 + 1], o0[4 * g4 + 2], o0[4 * g4 + 3]);
      float4 a1 = make_float4(o1[4 * g4], o1[4 * g4 + 1], o1[4 * g4 + 2], o1[4 * g4 + 3]);
      *reinterpret_cast<float4*>(P + 8 * g4 + 4 * hi) = a0;
      *reinterpret_cast<float4*>(P + 32 + 8 * g4 + 4 * hi) = a1;
    }
    if (hi == 0) { P[64] = m; P[65] = ls; }
  }
}

// merge the two kv-halves of the heavy q-tiles (flash-decode combine, exp2 domain)
__global__ void attn_merge(const float* __restrict__ part, ushort* __restrict__ attnout) {
  const int blk = blockIdx.x;
  const int row = threadIdx.x;
  const int bh = blk >> 3, qt = (blk & 7) + 8;
  const float* Pa = part + ((size_t)blk * 128 + row) * 72;
  const float* Pb = part + ((size_t)(256 + blk) * 128 + row) * 72;
  float mA = Pa[64], lsA = Pa[65], mB = Pb[64], lsB = Pb[65];
  float M = fmaxf(mA, mB);
  float ca = EXP2(mA - M), cb = EXP2(mB - M);
  float inv = 1.0f / (lsA * ca + lsB * cb);
  const int b = bh >> 4, h = bh & 15;
  const int q = qt * 128 + row;
  ushort* Op = attnout + ((size_t)b * S_LEN + q) * DM + h * HD;
#pragma unroll
  for (int dd = 0; dd < 64; dd += 4) {
    float4 va = *reinterpret_cast<const float4*>(Pa + dd);
    float4 vb = *reinterpret_cast<const float4*>(Pb + dd);
    ushort4v wv;
    wv[0] = f2b((va.x * ca + vb.x * cb) * inv);
    wv[1] = f2b((va.y * ca + vb.y * cb) * inv);
    wv[2] = f2b((va.z * ca + vb.z * cb) * inv);
    wv[3] = f2b((va.w * ca + vb.w * cb) * inv);
    *reinterpret_cast<ushort4v*>(Op + dd) = wv;
  }
}

// ----------------------------------------------------------------
extern "C" void kernel_launch(void* const* d_in, const int* in_sizes, int n_in,
                              void* d_out, int out_size, void* d_ws, size_t ws_size,
                              hipStream_t stream) {
  const float* x   = (const float*)d_in[0];
  const float* Wqa = (const float*)d_in[1];
  const float* Wka = (const float*)d_in[2];
  const float* Wqp = (const float*)d_in[3];
  const float* Wkp = (const float*)d_in[4];
  const float* Wv  = (const float*)d_in[5];
  const float* Wo  = (const float*)d_in[6];
  const float* sls = (const float*)d_in[7];

  char* ws = (char*)d_ws;
  ushort* x_bf = (ushort*)ws; ws += (size_t)NTOK * DM * 2;
  ushort* w_bf[6];
  for (int i = 0; i < 6; i++) { w_bf[i] = (ushort*)ws; ws += (size_t)DM * DM * 2; }
  ushort* qext = (ushort*)ws; ws += (size_t)NBH * S_LEN * 128 * 2;
  ushort* kext = (ushort*)ws; ws += (size_t)NBH * S_LEN * 128 * 2;
  ushort* vT   = (ushort*)ws; ws += (size_t)NBH * HD * S_LEN * 2;
  ushort* attn = (ushort*)ws; ws += (size_t)NTOK * DM * 2;
  float* part  = (float*)ws;  ws += (size_t)2 * 256 * 128 * 72 * 4;

  // 1. fp32 -> bf16 conversions (x + 6 weights)
  CvtArgs ca;
  ca.src[0] = x; ca.dst[0] = x_bf; ca.n[0] = NTOK * DM;
  const float* wsrc[6] = {Wqa, Wka, Wqp, Wkp, Wv, Wo};
  for (int i = 0; i < 6; i++) { ca.src[i + 1] = wsrc[i]; ca.dst[i + 1] = w_bf[i]; ca.n[i + 1] = DM * DM; }
  hipLaunchKernelGGL(cvt_kernel, dim3(512, 7), dim3(256), 0, stream, ca);

  // 2. fused projections: B1-in-registers, 32KB LDS dbuf -> 3 blocks/CU
  hipLaunchKernelGGL(qkproj_kernel, dim3(768), dim3(256), 0, stream,
                     x_bf, w_bf[0], w_bf[2], w_bf[1], w_bf[3], w_bf[4], sls,
                     qext, kext, vT);

  // 3. causal flash attention: XCD-local heads, heavy q-tiles kv-split, exp2 softmax
  hipLaunchKernelGGL(attn_kernel, dim3(768), dim3(256), 0, stream,
                     qext, kext, vT, attn, part);
  hipLaunchKernelGGL(attn_merge, dim3(256), dim3(128), 0, stream, part, attn);

  // 4. output projection -> fp32 d_out (XCD-swizzled flat grid, 4-buffer ring)
  hipLaunchKernelGGL(gemm_bt, dim3(256), dim3(256), 0, stream, attn, w_bf[5],
                     (float*)d_out, NTOK, DM, DM);
}

// Round 19
// 153.949 us; speedup vs baseline: 1.0558x; 1.0558x over previous
//
#include <hip/hip_runtime.h>
#include <hip/hip_bf16.h>
#include <math.h>

// Problem constants (fixed shapes from setup_inputs)
#define S_LEN 2048
#define NH 16
#define HD 64
#define DM 1024
#define NTOK 4096   // B*S
#define NBH 32      // B*NH

typedef __attribute__((ext_vector_type(8))) __bf16 bf16x8;
typedef __attribute__((ext_vector_type(8))) ushort ushort8;
typedef __attribute__((ext_vector_type(4))) ushort ushort4v;
typedef __attribute__((ext_vector_type(4))) float f32x4;
typedef __attribute__((ext_vector_type(16))) float f32x16;
typedef __attribute__((ext_vector_type(4))) uint u32x4;

__device__ __forceinline__ ushort f2b(float x) {
  __hip_bfloat16 h = __float2bfloat16(x);
  return *reinterpret_cast<ushort*>(&h);
}

__device__ __forceinline__ uint pk2(float lo, float hi) {
  return (uint)f2b(lo) | ((uint)f2b(hi) << 16);
}

// raw v_exp_f32 (exp2) — libm exp2f goes through __ocml with special-case handling
#define EXP2(x) __builtin_amdgcn_exp2f(x)

__device__ __forceinline__ void gload16b(const void* g, void* l) {
  __builtin_amdgcn_global_load_lds((const __attribute__((address_space(1))) void*)g,
                                   (__attribute__((address_space(3))) void*)l, 16, 0, 0);
}

#define MFMA16(a, b, c) __builtin_amdgcn_mfma_f32_16x16x32_bf16((a), (b), (c), 0, 0, 0)
#define MFMA32(a, b, c) __builtin_amdgcn_mfma_f32_32x32x16_bf16((a), (b), (c), 0, 0, 0)

// ---------------------------------------------------------------- convert fp32 -> bf16
struct CvtArgs {
  const float* src[7];
  ushort* dst[7];
  int n[7];
};

__global__ void cvt_kernel(CvtArgs a) {
  int arr = blockIdx.y;
  const float* s = a.src[arr];
  ushort* d = a.dst[arr];
  long n = a.n[arr];
  for (long i = ((long)blockIdx.x * 256 + threadIdx.x) * 8; i < n; i += 512L * 256 * 8) {
    float4 v0 = *reinterpret_cast<const float4*>(s + i);
    float4 v1 = *reinterpret_cast<const float4*>(s + i + 4);
    ushort8 r;
    r[0] = f2b(v0.x); r[1] = f2b(v0.y); r[2] = f2b(v0.z); r[3] = f2b(v0.w);
    r[4] = f2b(v1.x); r[5] = f2b(v1.y); r[6] = f2b(v1.z); r[7] = f2b(v1.w);
    *reinterpret_cast<ushort8*>(d + i) = r;
  }
}

// ---------------------------------------------------------------- fused QK/V projection
// (R15/R17 best config: 128x128xBK32, 256 threads, triple-buffer ring, counted vmcnt,
//  conflict-free slot swizzle, XCD-balanced grid, launch_bounds(256,2) — 120 VGPR,
//  NO spill. Lessons: (256,3) -> 84 VGPR -> spill (R16); B1-in-regs -> mixed vmcnt
//  kills the prefetch (R18); bigger tile -> loses cross-block overlap (R13).)
// q-side scale folds log2(e) so attention softmax runs in exp2 domain.
__global__ __launch_bounds__(256, 2) void qkproj_kernel(
    const ushort* __restrict__ A,
    const ushort* __restrict__ Wqa, const ushort* __restrict__ Wqp,
    const ushort* __restrict__ Wka, const ushort* __restrict__ Wkp,
    const ushort* __restrict__ Wv, const float* __restrict__ sls,
    ushort* __restrict__ qext, ushort* __restrict__ kext, ushort* __restrict__ vT) {
  __shared__ __align__(16) ushort Alds[3][4096];
  __shared__ __align__(16) ushort B0lds[3][4096];
  __shared__ __align__(16) ushort B1lds[3][4096];
  const int d = blockIdx.x;
  const int xc = d & 7, c = d >> 3;  // c in 0..95
  const int u = (c < 64) ? (xc * 64 + c) : (512 + xc * 32 + (c - 64));
  int z, bx, by;
  if (u < 512) { z = u >> 8; int v = u & 255; bx = v & 7; by = v >> 3; }
  else         { z = 2;      int v = u - 512; bx = v & 7; by = v >> 3; }
  const int t = threadIdx.x;
  const int lane = t & 63;
  const int wave = t >> 6;
  const int wm = wave >> 1, wn = wave & 1;
  const int l15 = lane & 15, g = lane >> 4;
  const int mbase = by * 128, nbase = bx * 128;
  const int K = DM;
  const int srow = t >> 2;
  const int sx = (srow >> 1) & 3;            // inverse source swizzle
  const int scol = (((t & 3) ^ sx)) * 8;
  const int xr = (l15 >> 1) & 3;             // read-side swizzle
  const ushort* Ag = A + (size_t)(mbase + srow) * K + scol;
  const ushort* Wa = (z == 0) ? Wqa : (z == 1) ? Wka : Wv;
  const ushort* Wp = (z == 0) ? Wqp : Wkp;
  const ushort* Wag = Wa + (size_t)(nbase + srow) * K + scol;
  const ushort* Wpg = (z < 2) ? (Wp + (size_t)(nbase + srow) * K + scol) : Wag;

  const int nk = K / 32;
  f32x4 accA[4][4] = {};

  if (z < 2) {
    f32x4 accP[4][4] = {};
    auto stage = [&](int buf, int kt) {
      gload16b(Ag + kt, &Alds[buf][t * 8]);
      gload16b(Ag + kt + (size_t)64 * K, &Alds[buf][t * 8 + 64 * 32]);
      gload16b(Wag + kt, &B0lds[buf][t * 8]);
      gload16b(Wag + kt + (size_t)64 * K, &B0lds[buf][t * 8 + 64 * 32]);
      gload16b(Wpg + kt, &B1lds[buf][t * 8]);
      gload16b(Wpg + kt + (size_t)64 * K, &B1lds[buf][t * 8 + 64 * 32]);
    };
    stage(0, 0);
    stage(1, 32);
    int cur = 0;
    for (int kt = 0; kt < nk; ++kt) {
      if (kt + 2 < nk) {
        int b2 = cur + 2; if (b2 >= 3) b2 -= 3;
        stage(b2, (kt + 2) * 32);
        asm volatile("s_waitcnt vmcnt(12)" ::: "memory");
      } else if (kt + 1 < nk) {
        asm volatile("s_waitcnt vmcnt(6)" ::: "memory");
      } else {
        asm volatile("s_waitcnt vmcnt(0)" ::: "memory");
      }
      __builtin_amdgcn_s_barrier();
      bf16x8 af[4], ba[4], bp[4];
#pragma unroll
      for (int i = 0; i < 4; i++)
        af[i] = *reinterpret_cast<const bf16x8*>(
            &Alds[cur][(wm * 64 + i * 16 + l15) * 32 + (g ^ xr) * 8]);
#pragma unroll
      for (int j = 0; j < 4; j++) {
        ba[j] = *reinterpret_cast<const bf16x8*>(
            &B0lds[cur][(wn * 64 + j * 16 + l15) * 32 + (g ^ xr) * 8]);
        bp[j] = *reinterpret_cast<const bf16x8*>(
            &B1lds[cur][(wn * 64 + j * 16 + l15) * 32 + (g ^ xr) * 8]);
      }
      __builtin_amdgcn_s_setprio(1);
#pragma unroll
      for (int i = 0; i < 4; i++)
#pragma unroll
        for (int j = 0; j < 4; j++) {
          accA[i][j] = MFMA16(af[i], ba[j], accA[i][j]);
          accP[i][j] = MFMA16(af[i], bp[j], accP[i][j]);
        }
      __builtin_amdgcn_s_setprio(0);
      __builtin_amdgcn_s_barrier();
      cur = (cur + 1 == 3) ? 0 : cur + 1;
    }
    const int row0 = mbase + wm * 64;
    const int h = (nbase >> 6) + wn;
    // q-scale folds exp(sls)/8 AND log2(e) -> attention exp becomes exp2
    const float scale = (z == 0) ? __expf(sls[h]) * 0.125f * 1.44269504f : 1.0f;
    ushort* ext = (z == 0) ? qext : kext;
#pragma unroll
    for (int i = 0; i < 4; i++) {
#pragma unroll
      for (int r = 0; r < 4; r++) {
        float sp[4];
        float ss = 0.0f;
#pragma unroll
        for (int j = 0; j < 4; j++) {
          float v = accA[i][j][r];
          sp[j] = fmaxf(v, 0.0f) + __logf(1.0f + __expf(-fabsf(v)));
          ss += sp[j] * sp[j];
        }
        ss += __shfl_xor(ss, 1);
        ss += __shfl_xor(ss, 2);
        ss += __shfl_xor(ss, 4);
        ss += __shfl_xor(ss, 8);
        float rn = rsqrtf(ss * (1.0f / 64.0f) + 1e-6f) * scale;
        const int token = row0 + i * 16 + g * 4 + r;
        const int bb = token >> 11, sidx = token & 2047;
        ushort* base = ext + (((size_t)(bb * NH + h) * S_LEN + sidx) << 7);
#pragma unroll
        for (int j = 0; j < 4; j++) {
          float e = __expf(2.0f * accP[i][j][r]);
          float th = 1.0f - 2.0f * __builtin_amdgcn_rcpf(e + 1.0f);
          float phi = 3.14159265358979f * th;
          float sn = __sinf(phi), cs = __cosf(phi);
          float a = sp[j] * rn;
          int dd = j * 16 + l15;
          base[dd] = f2b(a * cs);
          base[64 + dd] = f2b(a * sn);
        }
      }
    }
  } else {
    auto stage = [&](int buf, int kt) {
      gload16b(Ag + kt, &Alds[buf][t * 8]);
      gload16b(Ag + kt + (size_t)64 * K, &Alds[buf][t * 8 + 64 * 32]);
      gload16b(Wag + kt, &B0lds[buf][t * 8]);
      gload16b(Wag + kt + (size_t)64 * K, &B0lds[buf][t * 8 + 64 * 32]);
    };
    stage(0, 0);
    stage(1, 32);
    int cur = 0;
    for (int kt = 0; kt < nk; ++kt) {
      if (kt + 2 < nk) {
        int b2 = cur + 2; if (b2 >= 3) b2 -= 3;
        stage(b2, (kt + 2) * 32);
        asm volatile("s_waitcnt vmcnt(8)" ::: "memory");
      } else if (kt + 1 < nk) {
        asm volatile("s_waitcnt vmcnt(4)" ::: "memory");
      } else {
        asm volatile("s_waitcnt vmcnt(0)" ::: "memory");
      }
      __builtin_amdgcn_s_barrier();
      bf16x8 af[4], ba[4];
#pragma unroll
      for (int i = 0; i < 4; i++)
        af[i] = *reinterpret_cast<const bf16x8*>(
            &Alds[cur][(wm * 64 + i * 16 + l15) * 32 + (g ^ xr) * 8]);
#pragma unroll
      for (int j = 0; j < 4; j++)
        ba[j] = *reinterpret_cast<const bf16x8*>(
            &B0lds[cur][(wn * 64 + j * 16 + l15) * 32 + (g ^ xr) * 8]);
      __builtin_amdgcn_s_setprio(1);
#pragma unroll
      for (int i = 0; i < 4; i++)
#pragma unroll
        for (int j = 0; j < 4; j++)
          accA[i][j] = MFMA16(af[i], ba[j], accA[i][j]);
      __builtin_amdgcn_s_setprio(0);
      __builtin_amdgcn_s_barrier();
      cur = (cur + 1 == 3) ? 0 : cur + 1;
    }
    const int row0 = mbase + wm * 64, col0 = nbase + wn * 64;
#pragma unroll
    for (int i = 0; i < 4; i++)
#pragma unroll
      for (int j = 0; j < 4; j++) {
        int col = col0 + j * 16 + l15;
        int h = col >> 6, hd = col & 63;
        int t0 = row0 + i * 16 + g * 4;
        int bb = t0 >> 11, s0 = t0 & 2047;
        ushort4v w;
#pragma unroll
        for (int r = 0; r < 4; r++) w[r] = f2b(accA[i][j][r]);
        *reinterpret_cast<ushort4v*>(
            &vT[(((size_t)(bb * NH + h) * HD + hd) << 11) + s0]) = w;
      }
  }
}

// ---------------------------------------------------------------- GEMM (Wo projection)
__global__ __launch_bounds__(256) void gemm_bt(const ushort* __restrict__ A,
                                               const ushort* __restrict__ W,
                                               float* __restrict__ Cout,
                                               int M, int N, int K) {
  __shared__ __align__(16) ushort Alds[4][4096];
  __shared__ __align__(16) ushort Blds[4][4096];
  const int d = blockIdx.x;
  const int u = (d & 7) * 32 + (d >> 3);
  const int bx = u & 7, by = u >> 3;
  const int t = threadIdx.x;
  const int lane = t & 63;
  const int wave = t >> 6;
  const int wm = wave >> 1, wn = wave & 1;
  const int l15 = lane & 15, g = lane >> 4;
  const int mbase = by * 128, nbase = bx * 128;
  const int srow = t >> 2;
  const int sx = (srow >> 1) & 3;
  const int scol = (((t & 3) ^ sx)) * 8;
  const int xr = (l15 >> 1) & 3;
  const ushort* Ag = A + (size_t)(mbase + srow) * K + scol;
  const ushort* Wg = W + (size_t)(nbase + srow) * K + scol;
  auto stage = [&](int buf, int kt) {
    gload16b(Ag + kt, &Alds[buf][t * 8]);
    gload16b(Ag + kt + (size_t)64 * K, &Alds[buf][t * 8 + 64 * 32]);
    gload16b(Wg + kt, &Blds[buf][t * 8]);
    gload16b(Wg + kt + (size_t)64 * K, &Blds[buf][t * 8 + 64 * 32]);
  };
  const int nk = K / 32;
  stage(0, 0);
  stage(1, 32);
  stage(2, 64);
  f32x4 acc[4][4] = {};
  for (int kt = 0; kt < nk; ++kt) {
    const int cur = kt & 3;
    if (kt + 3 < nk) {
      stage((cur + 3) & 3, (kt + 3) * 32);
      asm volatile("s_waitcnt vmcnt(12)" ::: "memory");
    } else if (kt + 2 < nk) {
      asm volatile("s_waitcnt vmcnt(8)" ::: "memory");
    } else if (kt + 1 < nk) {
      asm volatile("s_waitcnt vmcnt(4)" ::: "memory");
    } else {
      asm volatile("s_waitcnt vmcnt(0)" ::: "memory");
    }
    __builtin_amdgcn_s_barrier();
    bf16x8 af[4], bfr[4];
#pragma unroll
    for (int i = 0; i < 4; i++)
      af[i] = *reinterpret_cast<const bf16x8*>(
          &Alds[cur][(wm * 64 + i * 16 + l15) * 32 + (g ^ xr) * 8]);
#pragma unroll
    for (int j = 0; j < 4; j++)
      bfr[j] = *reinterpret_cast<const bf16x8*>(
          &Blds[cur][(wn * 64 + j * 16 + l15) * 32 + (g ^ xr) * 8]);
    __builtin_amdgcn_s_setprio(1);
#pragma unroll
    for (int i = 0; i < 4; i++)
#pragma unroll
      for (int j = 0; j < 4; j++)
        acc[i][j] = MFMA16(af[i], bfr[j], acc[i][j]);
    __builtin_amdgcn_s_setprio(0);
    __builtin_amdgcn_s_barrier();
  }
  const int row0 = mbase + wm * 64, col0 = nbase + wn * 64;
#pragma unroll
  for (int i = 0; i < 4; i++)
#pragma unroll
    for (int j = 0; j < 4; j++)
#pragma unroll
      for (int r = 0; r < 4; r++) {
        int row = row0 + i * 16 + g * 4 + r;
        int col = col0 + j * 16 + l15;
        Cout[(size_t)row * N + col] = acc[i][j][r];
      }
}

// ---------------------------------------------------------------- causal flash attention
// Softmax in exp2 domain via raw v_exp_f32 (log2(e) folded into q-scale).
// Defer-max threshold 11.5416 (= 8*log2e, P bound e^8 unchanged).
__device__ __forceinline__ void stage_kv(const char* Kp, const char* Vp, int kb,
                                         char* buf, int wave, int lane) {
#pragma unroll
  for (int c = 0; c < 4; c++) {
    int i = wave * 4 + c;
    int kvl = i * 4 + (lane >> 4);
    int slot = (lane & 15) ^ (kvl & 7);
    gload16b(Kp + (size_t)(kb + kvl) * 256 + slot * 16, buf + i * 1024);
  }
#pragma unroll
  for (int c = 0; c < 2; c++) {
    int i = wave * 2 + c;
    int hd = i * 8 + (lane >> 3);
    int slot = (lane & 7) ^ (hd & 7);
    gload16b(Vp + (size_t)hd * (S_LEN * 2) + (size_t)kb * 2 + slot * 16,
             buf + 16384 + i * 1024);
  }
}

__global__ __launch_bounds__(256, 3) void attn_kernel(const ushort* __restrict__ qext,
                                                      const ushort* __restrict__ kext,
                                                      const ushort* __restrict__ vT,
                                                      ushort* __restrict__ attnout,
                                                      float* __restrict__ part) {
  __shared__ __align__(16) char lds[2][24576];
  const int d = blockIdx.x;
  const int xcd = d & 7, c = d >> 3;          // c in 0..95
  const int bh = xcd * 4 + (c & 3);           // 4 heads per XCD
  const int w = c >> 2;                       // 0..23
  int qt, t0, t1, half;
  bool split;
  if (w < 8) { qt = w; t0 = 0; t1 = 2 * qt + 1; split = false; half = 0; }
  else {
    int ww = w - 8;
    qt = 8 + (ww >> 1); half = ww & 1; split = true;
    if (half == 0) { t0 = 0; t1 = qt; } else { t0 = qt + 1; t1 = 2 * qt + 1; }
  }
  const int b = bh >> 4, h = bh & 15;
  const int wave = threadIdx.x >> 6, lane = threadIdx.x & 63;
  const int l31 = lane & 31, hi = lane >> 5;
  const int qb = qt * 128;
  const int qw = qb + wave * 32;
  const int qa = qw + l31;
  const char* Kp = (const char*)(kext + (size_t)bh * S_LEN * 128);
  const char* Vp = (const char*)(vT + (size_t)bh * HD * S_LEN);
  const ushort* Qp = qext + (size_t)bh * S_LEN * 128;
  const int ksw = l31 & 7;

  stage_kv(Kp, Vp, t0 << 6, lds[0], wave, lane);
  bf16x8 qf[8];
#pragma unroll
  for (int s = 0; s < 8; s++)
    qf[s] = *reinterpret_cast<const bf16x8*>(&Qp[(size_t)qa * 128 + s * 16 + hi * 8]);

  f32x16 o0 = {}, o1 = {};
  float m = -1e30f, ls = 0.0f;

  for (int t = t0; t <= t1; ++t) {
    const int cur = (t - t0) & 1;
    const int kb = t << 6;
    if (t < t1) {
      stage_kv(Kp, Vp, (t + 1) << 6, lds[cur ^ 1], wave, lane);
      asm volatile("s_waitcnt vmcnt(6)" ::: "memory");
    } else {
      asm volatile("s_waitcnt vmcnt(0)" ::: "memory");
    }
    __builtin_amdgcn_s_barrier();

    const char* Kb = lds[cur];
    const char* Vb = lds[cur] + 16384;

    f32x16 st0 = {}, st1 = {};
    __builtin_amdgcn_s_setprio(1);
#pragma unroll
    for (int s = 0; s < 8; s++) {
      int sl = ((s * 2 + hi) ^ ksw) << 4;
      bf16x8 k0 = *(const bf16x8*)(Kb + l31 * 256 + sl);
      bf16x8 k1 = *(const bf16x8*)(Kb + (32 + l31) * 256 + sl);
      st0 = MFMA32(k0, qf[s], st0);
      st1 = MFMA32(k1, qf[s], st1);
    }
    __builtin_amdgcn_s_setprio(0);

    if (kb + 64 > qw) {
#pragma unroll
      for (int r = 0; r < 16; r++) {
        int kv = kb + (r & 3) + 8 * (r >> 2) + 4 * hi;
        if (kv > qa) st0[r] = -1e30f;
        if (kv + 32 > qa) st1[r] = -1e30f;
      }
    }
    float pm = -1e30f;
#pragma unroll
    for (int r = 0; r < 16; r++) pm = fmaxf(pm, fmaxf(st0[r], st1[r]));
    pm = fmaxf(pm, __shfl_xor(pm, 32));
    if (!__all(pm <= m + 11.5416f)) {   // 8 * log2(e): bound e^8, exp2 domain
      float mn = fmaxf(m, pm);
      float corr = EXP2(m - mn);
      m = mn;
      ls *= corr;
#pragma unroll
      for (int r = 0; r < 16; r++) { o0[r] *= corr; o1[r] *= corr; }
    }
    float ssum = 0.0f;
#pragma unroll
    for (int r = 0; r < 16; r++) {
      st0[r] = EXP2(st0[r] - m);
      st1[r] = EXP2(st1[r] - m);
      ssum += st0[r] + st1[r];
    }
    ssum += __shfl_xor(ssum, 32);
    ls += ssum;

    u32x4 pb[4];
#pragma unroll
    for (int hf = 0; hf < 2; hf++) {
      const f32x16& st = hf ? st1 : st0;
      uint cA0 = pk2(st[0], st[1]),  cA1 = pk2(st[2], st[3]);
      uint cB0 = pk2(st[4], st[5]),  cB1 = pk2(st[6], st[7]);
      uint cC0 = pk2(st[8], st[9]),  cC1 = pk2(st[10], st[11]);
      uint cD0 = pk2(st[12], st[13]), cD1 = pk2(st[14], st[15]);
      uint xA0 = __shfl_xor(cA0, 32), xA1 = __shfl_xor(cA1, 32);
      uint xB0 = __shfl_xor(cB0, 32), xB1 = __shfl_xor(cB1, 32);
      uint xC0 = __shfl_xor(cC0, 32), xC1 = __shfl_xor(cC1, 32);
      uint xD0 = __shfl_xor(cD0, 32), xD1 = __shfl_xor(cD1, 32);
      u32x4 lo, hi4;
      lo[0] = cA0; lo[1] = cA1; lo[2] = xA0; lo[3] = xA1;
      hi4[0] = xB0; hi4[1] = xB1; hi4[2] = cB0; hi4[3] = cB1;
      pb[hf * 2] = hi ? hi4 : lo;
      u32x4 lo2, hi2;
      lo2[0] = cC0; lo2[1] = cC1; lo2[2] = xC0; lo2[3] = xC1;
      hi2[0] = xD0; hi2[1] = xD1; hi2[2] = cD0; hi2[3] = cD1;
      pb[hf * 2 + 1] = hi ? hi2 : lo2;
    }
    __builtin_amdgcn_s_setprio(1);
#pragma unroll
    for (int ks = 0; ks < 4; ks++) {
      int sl = ((ks * 2 + hi) ^ ksw) << 4;
      bf16x8 v0 = *(const bf16x8*)(Vb + l31 * 128 + sl);
      bf16x8 v1 = *(const bf16x8*)(Vb + (32 + l31) * 128 + sl);
      bf16x8 pbb = *reinterpret_cast<const bf16x8*>(&pb[ks]);
      o0 = MFMA32(v0, pbb, o0);
      o1 = MFMA32(v1, pbb, o1);
    }
    __builtin_amdgcn_s_setprio(0);
    __builtin_amdgcn_s_barrier();
  }

  if (!split) {
    float inv = 1.0f / ls;
    ushort* Op = attnout + ((size_t)b * S_LEN + qa) * DM + h * HD;
#pragma unroll
    for (int g4 = 0; g4 < 4; g4++) {
      ushort4v w0, w1;
#pragma unroll
      for (int jj = 0; jj < 4; jj++) {
        w0[jj] = f2b(o0[4 * g4 + jj] * inv);
        w1[jj] = f2b(o1[4 * g4 + jj] * inv);
      }
      *reinterpret_cast<ushort4v*>(Op + 8 * g4 + 4 * hi) = w0;
      *reinterpret_cast<ushort4v*>(Op + 32 + 8 * g4 + 4 * hi) = w1;
    }
  } else {
    float* P = part + ((size_t)(half * 256 + bh * 8 + (qt - 8)) * 128
                       + (wave * 32 + l31)) * 72;
#pragma unroll
    for (int g4 = 0; g4 < 4; g4++) {
      float4 a0 = make_float4(o0[4 * g4], o0[4 * g4 + 1], o0[4 * g4 + 2], o0[4 * g4 + 3]);
      float4 a1 = make_float4(o1[4 * g4], o1[4 * g4 + 1], o1[4 * g4 + 2], o1[4 * g4 + 3]);
      *reinterpret_cast<float4*>(P + 8 * g4 + 4 * hi) = a0;
      *reinterpret_cast<float4*>(P + 32 + 8 * g4 + 4 * hi) = a1;
    }
    if (hi == 0) { P[64] = m; P[65] = ls; }
  }
}

// merge the two kv-halves of the heavy q-tiles (flash-decode combine, exp2 domain)
__global__ void attn_merge(const float* __restrict__ part, ushort* __restrict__ attnout) {
  const int blk = blockIdx.x;
  const int row = threadIdx.x;
  const int bh = blk >> 3, qt = (blk & 7) + 8;
  const float* Pa = part + ((size_t)blk * 128 + row) * 72;
  const float* Pb = part + ((size_t)(256 + blk) * 128 + row) * 72;
  float mA = Pa[64], lsA = Pa[65], mB = Pb[64], lsB = Pb[65];
  float M = fmaxf(mA, mB);
  float ca = EXP2(mA - M), cb = EXP2(mB - M);
  float inv = 1.0f / (lsA * ca + lsB * cb);
  const int b = bh >> 4, h = bh & 15;
  const int q = qt * 128 + row;
  ushort* Op = attnout + ((size_t)b * S_LEN + q) * DM + h * HD;
#pragma unroll
  for (int dd = 0; dd < 64; dd += 4) {
    float4 va = *reinterpret_cast<const float4*>(Pa + dd);
    float4 vb = *reinterpret_cast<const float4*>(Pb + dd);
    ushort4v wv;
    wv[0] = f2b((va.x * ca + vb.x * cb) * inv);
    wv[1] = f2b((va.y * ca + vb.y * cb) * inv);
    wv[2] = f2b((va.z * ca + vb.z * cb) * inv);
    wv[3] = f2b((va.w * ca + vb.w * cb) * inv);
    *reinterpret_cast<ushort4v*>(Op + dd) = wv;
  }
}

// ----------------------------------------------------------------
extern "C" void kernel_launch(void* const* d_in, const int* in_sizes, int n_in,
                              void* d_out, int out_size, void* d_ws, size_t ws_size,
                              hipStream_t stream) {
  const float* x   = (const float*)d_in[0];
  const float* Wqa = (const float*)d_in[1];
  const float* Wka = (const float*)d_in[2];
  const float* Wqp = (const float*)d_in[3];
  const float* Wkp = (const float*)d_in[4];
  const float* Wv  = (const float*)d_in[5];
  const float* Wo  = (const float*)d_in[6];
  const float* sls = (const float*)d_in[7];

  char* ws = (char*)d_ws;
  ushort* x_bf = (ushort*)ws; ws += (size_t)NTOK * DM * 2;
  ushort* w_bf[6];
  for (int i = 0; i < 6; i++) { w_bf[i] = (ushort*)ws; ws += (size_t)DM * DM * 2; }
  ushort* qext = (ushort*)ws; ws += (size_t)NBH * S_LEN * 128 * 2;
  ushort* kext = (ushort*)ws; ws += (size_t)NBH * S_LEN * 128 * 2;
  ushort* vT   = (ushort*)ws; ws += (size_t)NBH * HD * S_LEN * 2;
  ushort* attn = (ushort*)ws; ws += (size_t)NTOK * DM * 2;
  float* part  = (float*)ws;  ws += (size_t)2 * 256 * 128 * 72 * 4;

  // 1. fp32 -> bf16 conversions (x + 6 weights)
  CvtArgs ca;
  ca.src[0] = x; ca.dst[0] = x_bf; ca.n[0] = NTOK * DM;
  const float* wsrc[6] = {Wqa, Wka, Wqp, Wkp, Wv, Wo};
  for (int i = 0; i < 6; i++) { ca.src[i + 1] = wsrc[i]; ca.dst[i + 1] = w_bf[i]; ca.n[i + 1] = DM * DM; }
  hipLaunchKernelGGL(cvt_kernel, dim3(512, 7), dim3(256), 0, stream, ca);

  // 2. fused projections (R15/R17 best config), XCD-balanced swizzled flat grid
  hipLaunchKernelGGL(qkproj_kernel, dim3(768), dim3(256), 0, stream,
                     x_bf, w_bf[0], w_bf[2], w_bf[1], w_bf[3], w_bf[4], sls,
                     qext, kext, vT);

  // 3. causal flash attention: XCD-local heads, heavy q-tiles kv-split, exp2 softmax
  hipLaunchKernelGGL(attn_kernel, dim3(768), dim3(256), 0, stream,
                     qext, kext, vT, attn, part);
  hipLaunchKernelGGL(attn_merge, dim3(256), dim3(128), 0, stream, part, attn);

  // 4. output projection -> fp32 d_out (XCD-swizzled flat grid, 4-buffer ring)
  hipLaunchKernelGGL(gemm_bt, dim3(256), dim3(256), 0, stream, attn, w_bf[5],
                     (float*)d_out, NTOK, DM, DM);
}